// Round 1
// baseline (1173.123 us; speedup 1.0000x reference)
//
#include <hip/hip_runtime.h>
#include <math.h>

#define SEQ 4096
#define DIM 256
#define NH 8
#define DHD 32
#define FFD 1024
#define NLAYER 4

__device__ __forceinline__ float gelu_f(float x){
  const float c = 0.7978845608028654f; // sqrt(2/pi)
  float x3 = x*x*x;
  return 0.5f * x * (1.0f + tanhf(c*(x + 0.044715f*x3)));
}

// LayerNorm (no affine): one 64-lane wave per row of 256 floats; 4 rows/block.
__global__ __launch_bounds__(256) void ln_kernel(const float* __restrict__ x,
                                                 float* __restrict__ y){
  int row  = blockIdx.x*4 + (threadIdx.x>>6);
  int lane = threadIdx.x & 63;
  const float4* xr = (const float4*)(x + (size_t)row*DIM);
  float4 v = xr[lane];
  float s  = v.x+v.y+v.z+v.w;
  float sq = v.x*v.x+v.y*v.y+v.z*v.z+v.w*v.w;
  #pragma unroll
  for(int off=32; off>0; off>>=1){
    s  += __shfl_down(s, off);
    sq += __shfl_down(sq, off);
  }
  s = __shfl(s, 0); sq = __shfl(sq, 0);
  float mean = s * (1.0f/DIM);
  float var  = sq * (1.0f/DIM) - mean*mean;
  float rinv = rsqrtf(var + 1e-5f);
  float4 o;
  o.x=(v.x-mean)*rinv; o.y=(v.y-mean)*rinv; o.z=(v.z-mean)*rinv; o.w=(v.w-mean)*rinv;
  ((float4*)(y + (size_t)row*DIM))[lane] = o;
}

// C[M,N] = act(A[M,K] @ W[K,N] + bias[N] (+ R[M,N]))
// 64x64 tile, BK=16, 256 threads, 4x4 microtile per thread.
__global__ __launch_bounds__(256) void gemm_kernel(const float* __restrict__ A,
    const float* __restrict__ W, const float* __restrict__ bias,
    const float* __restrict__ R, float* __restrict__ C,
    int M, int N, int K, int act){
  __shared__ float As[16][68];
  __shared__ float Bs[16][68];
  int tid = threadIdx.x;
  int m0 = blockIdx.y*64, n0 = blockIdx.x*64;
  int a_m = tid>>4, a_k = tid&15;   // A loader: 16 consecutive tids -> 16 consecutive k
  int b_k = tid>>6, b_n = tid&63;   // B loader: 64 consecutive tids -> 64 consecutive n
  int tx = tid&15, ty = tid>>4;
  float acc[4][4] = {};
  for(int k0=0; k0<K; k0+=16){
    #pragma unroll
    for(int i=0;i<4;i++)
      As[a_k][a_m+16*i] = A[(size_t)(m0+a_m+16*i)*K + k0 + a_k];
    #pragma unroll
    for(int i=0;i<4;i++)
      Bs[b_k+4*i][b_n] = W[(size_t)(k0+b_k+4*i)*N + n0 + b_n];
    __syncthreads();
    #pragma unroll
    for(int kk=0;kk<16;kk++){
      float a[4], b[4];
      #pragma unroll
      for(int i=0;i<4;i++) a[i]=As[kk][ty*4+i];
      #pragma unroll
      for(int j=0;j<4;j++) b[j]=Bs[kk][tx*4+j];
      #pragma unroll
      for(int i=0;i<4;i++)
        #pragma unroll
        for(int j=0;j<4;j++)
          acc[i][j] = fmaf(a[i], b[j], acc[i][j]);
    }
    __syncthreads();
  }
  #pragma unroll
  for(int i=0;i<4;i++){
    int mm = m0 + ty*4 + i;
    #pragma unroll
    for(int j=0;j<4;j++){
      int nn = n0 + tx*4 + j;
      float c = acc[i][j] + bias[nn];
      if (R)   c += R[(size_t)mm*N + nn];
      if (act) c = gelu_f(c);
      C[(size_t)mm*N + nn] = c;
    }
  }
}

// Sliding-window attention, flash-style online softmax.
// Grid: (SEQ/64, NH). Block 256. Each block: 64 queries x 1 head.
// Thread (r = tid/4, g = tid%4): owns q-row r, dh slice [g*8, g*8+8), and
// computes score chunk j in [g*16, g*16+16) per 64-key tile.
__global__ __launch_bounds__(256) void attn_kernel(const float* __restrict__ q,
    const float* __restrict__ k, const float* __restrict__ v,
    float* __restrict__ out){
  int q0 = blockIdx.x * 64;
  int h  = blockIdx.y;
  int tid = threadIdx.x;
  int r = tid >> 2, g = tid & 3, c0 = g*8;
  __shared__ float Ks[64][33];   // pad 33: score-phase reads 2-way max (free)
  __shared__ float Vs[64][36];   // pad 36: keeps 16B alignment for float4 reads
  __shared__ float Ss[64][66];

  float qreg[32];
  {
    const float* qp = q + (size_t)(q0 + r)*DIM + h*DHD;
    #pragma unroll
    for(int d=0; d<32; d+=4){
      float4 t = *(const float4*)(qp + d);
      qreg[d]=t.x; qreg[d+1]=t.y; qreg[d+2]=t.z; qreg[d+3]=t.w;
    }
  }
  const float scale = 0.17677669529663687f; // 1/sqrt(32)
  float m = -INFINITY, l = 0.f;
  float o[8];
  #pragma unroll
  for(int i=0;i<8;i++) o[i]=0.f;

  for(int kt = q0 - 256; kt <= q0 + 256; kt += 64){
    if (kt < 0 || kt >= SEQ) continue;   // kt is block-uniform: barriers stay uniform
    __syncthreads();  // protect Ks/Vs/Ss from previous iteration's readers
    for (int idx = tid; idx < 64*32; idx += 256){
      int rr = idx >> 5, dd = idx & 31;
      Ks[rr][dd] = k[(size_t)(kt+rr)*DIM + h*DHD + dd];
      Vs[rr][dd] = v[(size_t)(kt+rr)*DIM + h*DHD + dd];
    }
    __syncthreads();

    float smax = -INFINITY;
    float sc[16];
    #pragma unroll
    for(int jj=0; jj<16; jj++){
      int j = g*16 + jj;
      float s = 0.f;
      #pragma unroll
      for(int d=0; d<32; d++) s = fmaf(qreg[d], Ks[j][d], s);
      s *= scale;
      int diff = (q0 + r) - (kt + j); if (diff < 0) diff = -diff;
      if (diff > 256) s = -INFINITY;
      sc[jj] = s;
      smax = fmaxf(smax, s);
    }
    smax = fmaxf(smax, __shfl_xor(smax, 1));
    smax = fmaxf(smax, __shfl_xor(smax, 2));
    float new_m = fmaxf(m, smax);
    float alpha = expf(m - new_m);       // m=-inf first tile -> alpha=0
    float rowsum = 0.f;
    #pragma unroll
    for(int jj=0;jj<16;jj++){
      float p = expf(sc[jj] - new_m);
      Ss[r][g*16+jj] = p;
      rowsum += p;
    }
    rowsum += __shfl_xor(rowsum,1);
    rowsum += __shfl_xor(rowsum,2);
    l = l*alpha + rowsum;
    m = new_m;
    #pragma unroll
    for(int i=0;i<8;i++) o[i]*=alpha;
    __syncthreads();  // Ss visible across (paranoia: producers are same wave)

    for(int j=0;j<64;j++){
      float pj = Ss[r][j];
      float4 v0 = *(const float4*)&Vs[j][c0];
      float4 v1 = *(const float4*)&Vs[j][c0+4];
      o[0] = fmaf(pj, v0.x, o[0]); o[1] = fmaf(pj, v0.y, o[1]);
      o[2] = fmaf(pj, v0.z, o[2]); o[3] = fmaf(pj, v0.w, o[3]);
      o[4] = fmaf(pj, v1.x, o[4]); o[5] = fmaf(pj, v1.y, o[5]);
      o[6] = fmaf(pj, v1.z, o[6]); o[7] = fmaf(pj, v1.w, o[7]);
    }
  }
  float rl = 1.0f / l;
  float* op = out + (size_t)(q0+r)*DIM + h*DHD + c0;
  #pragma unroll
  for(int i=0;i<8;i++) op[i] = o[i]*rl;
}

extern "C" void kernel_launch(void* const* d_in, const int* in_sizes, int n_in,
                              void* d_out, int out_size, void* d_ws, size_t ws_size,
                              hipStream_t stream) {
  const float* x  = (const float*)d_in[0];
  const float* wq = (const float*)d_in[1];
  const float* bq = (const float*)d_in[2];
  const float* wk = (const float*)d_in[3];
  const float* bk = (const float*)d_in[4];
  const float* wv = (const float*)d_in[5];
  const float* bv = (const float*)d_in[6];
  const float* wo = (const float*)d_in[7];
  const float* bo = (const float*)d_in[8];
  const float* w1 = (const float*)d_in[9];
  const float* b1 = (const float*)d_in[10];
  const float* w2 = (const float*)d_in[11];
  const float* b2 = (const float*)d_in[12];
  float* out = (float*)d_out;
  float* ws  = (float*)d_ws;

  const size_t SZ = (size_t)SEQ * DIM;      // 1M floats
  float* nbuf = ws;            // LN output; later reused as attention output
  float* qb   = ws + SZ;       // q; later reused as h1 (post-attn residual)
  float* kb   = ws + 2*SZ;     // k; later reused as h2 (post-norm)
  float* vb   = ws + 3*SZ;     // v
  float* ffb  = ws + 4*SZ;     // 4M floats (4096x1024)
  float* hb   = ws + 8*SZ;     // layer output carry

  const dim3 blk(256);
  const dim3 g_ln(SEQ/4);
  const dim3 g_g256(DIM/64, SEQ/64);   // N=256 GEMMs
  const dim3 g_g1024(FFD/64, SEQ/64);  // N=1024 GEMM
  const dim3 g_attn(SEQ/64, NH);

  for (int l = 0; l < NLAYER; l++){
    const float* hin = (l == 0) ? x : hb;
    const float* lwq = wq + (size_t)l*DIM*DIM;
    const float* lwk = wk + (size_t)l*DIM*DIM;
    const float* lwv = wv + (size_t)l*DIM*DIM;
    const float* lwo = wo + (size_t)l*DIM*DIM;
    const float* lw1 = w1 + (size_t)l*DIM*FFD;
    const float* lw2 = w2 + (size_t)l*DIM*FFD;
    const float* lbq = bq + (size_t)l*DIM;
    const float* lbk = bk + (size_t)l*DIM;
    const float* lbv = bv + (size_t)l*DIM;
    const float* lbo = bo + (size_t)l*DIM;
    const float* lb1 = b1 + (size_t)l*FFD;
    const float* lb2 = b2 + (size_t)l*DIM;

    // n = LN(h)
    ln_kernel<<<g_ln, blk, 0, stream>>>(hin, nbuf);
    // q,k,v = n@W + b
    gemm_kernel<<<g_g256, blk, 0, stream>>>(nbuf, lwq, lbq, nullptr, qb, SEQ, DIM, DIM, 0);
    gemm_kernel<<<g_g256, blk, 0, stream>>>(nbuf, lwk, lbk, nullptr, kb, SEQ, DIM, DIM, 0);
    gemm_kernel<<<g_g256, blk, 0, stream>>>(nbuf, lwv, lbv, nullptr, vb, SEQ, DIM, DIM, 0);
    // attention -> nbuf (n is dead)
    attn_kernel<<<g_attn, blk, 0, stream>>>(qb, kb, vb, nbuf);
    // h1 = h + attn@wo + bo   (write to qb; q is dead)
    gemm_kernel<<<g_g256, blk, 0, stream>>>(nbuf, lwo, lbo, hin, qb, SEQ, DIM, DIM, 0);
    // h2 = LN(h1)  (write to kb; k is dead)
    ln_kernel<<<g_ln, blk, 0, stream>>>(qb, kb);
    // ff = gelu(h2@w1 + b1)
    gemm_kernel<<<g_g1024, blk, 0, stream>>>(kb, lw1, lb1, nullptr, ffb, SEQ, FFD, DIM, 1);
    // h_out = h2 + ff@w2 + b2
    float* hout = (l == NLAYER-1) ? out : hb;
    gemm_kernel<<<g_g256, blk, 0, stream>>>(ffb, lw2, lb2, kb, hout, SEQ, DIM, FFD, 0);
  }
}

// Round 2
// 619.512 us; speedup vs baseline: 1.8936x; 1.8936x over previous
//
#include <hip/hip_runtime.h>
#include <math.h>

#define SEQ 4096
#define DIM 256
#define NH 8
#define DHD 32
#define FFD 1024
#define NLAYER 4

typedef unsigned short ushort_t;
typedef __attribute__((ext_vector_type(8))) short bf16x8;
typedef __attribute__((ext_vector_type(4))) float f32x4;

__device__ __forceinline__ float gelu_f(float x){
  const float c = 0.7978845608028654f; // sqrt(2/pi)
  float x3 = x*x*x;
  return 0.5f * x * (1.0f + tanhf(c*(x + 0.044715f*x3)));
}

__device__ __forceinline__ ushort_t f2b(float f){
  union { float f; unsigned u; } x; x.f = f;
  unsigned r = x.u + 0x7FFF + ((x.u >> 16) & 1);   // RNE
  return (ushort_t)(r >> 16);
}

// ---------------- weight convert + transpose: W[K][N] fp32 -> Wt[N][K] bf16 --
// grid 768 blocks x 256 thr. b<256: qkvo (4 mats x 4 layers x 16 tiles of 64x64)
// b in [256,512): w1 (K=256,N=1024); b in [512,768): w2 (K=1024,N=256).
__global__ __launch_bounds__(256) void wconv_kernel(
    const float* __restrict__ wq, const float* __restrict__ wk,
    const float* __restrict__ wv, const float* __restrict__ wo,
    const float* __restrict__ w1, const float* __restrict__ w2,
    ushort_t* __restrict__ wt){
  __shared__ ushort_t tile[64][65];
  int b = blockIdx.x, tid = threadIdx.x;
  const float* src; ushort_t* dst; int K, N, tk, tn;
  if (b < 256){
    int m = b>>6, rem = b&63, l = rem>>4, t = rem&15;
    K = 256; N = 256; tk = t>>2; tn = t&3;
    const float* s4 = (m==0)?wq:(m==1)?wk:(m==2)?wv:wo;
    src = s4 + (size_t)l*65536;
    dst = wt + (size_t)(m*NLAYER + l)*65536;
  } else if (b < 512){
    int rem = b-256, l = rem>>6, t = rem&63;
    K = 256; N = 1024; tk = t>>4; tn = t&15;
    src = w1 + (size_t)l*262144;
    dst = wt + 1048576 + (size_t)l*262144;
  } else {
    int rem = b-512, l = rem>>6, t = rem&63;
    K = 1024; N = 256; tk = t>>2; tn = t&3;
    src = w2 + (size_t)l*262144;
    dst = wt + 2097152 + (size_t)l*262144;
  }
  int k0 = tk*64, n0 = tn*64;
  #pragma unroll
  for (int i=0;i<16;i++){
    int idx = tid + 256*i, row = idx>>6, col = idx&63;
    tile[row][col] = f2b(src[(size_t)(k0+row)*N + n0+col]);
  }
  __syncthreads();
  #pragma unroll
  for (int i=0;i<16;i++){
    int idx = tid + 256*i, nrow = idx>>6, kcol = idx&63;
    dst[(size_t)(n0+nrow)*K + k0+kcol] = tile[kcol][nrow];
  }
}

// ---------------- LayerNorm: fp32 in, optional fp32 + bf16 out ---------------
__global__ __launch_bounds__(256) void ln_kernel(const float* __restrict__ x,
    float* __restrict__ yf, ushort_t* __restrict__ yb){
  int row  = blockIdx.x*4 + (threadIdx.x>>6);
  int lane = threadIdx.x & 63;
  const float4* xr = (const float4*)(x + (size_t)row*DIM);
  float4 v = xr[lane];
  float s  = v.x+v.y+v.z+v.w;
  float sq = v.x*v.x+v.y*v.y+v.z*v.z+v.w*v.w;
  #pragma unroll
  for(int off=32; off>0; off>>=1){
    s  += __shfl_down(s, off);
    sq += __shfl_down(sq, off);
  }
  s = __shfl(s, 0); sq = __shfl(sq, 0);
  float mean = s * (1.0f/DIM);
  float var  = sq * (1.0f/DIM) - mean*mean;
  float rinv = rsqrtf(var + 1e-5f);
  float4 o;
  o.x=(v.x-mean)*rinv; o.y=(v.y-mean)*rinv; o.z=(v.z-mean)*rinv; o.w=(v.w-mean)*rinv;
  if (yf) ((float4*)(yf + (size_t)row*DIM))[lane] = o;
  if (yb){
    ushort_t* yp = yb + (size_t)row*DIM + lane*4;
    yp[0]=f2b(o.x); yp[1]=f2b(o.y); yp[2]=f2b(o.z); yp[3]=f2b(o.w);
  }
}

// ---------------- bf16 MFMA GEMM core: C = act(A @ Wt^T + bias (+R)) ---------
// A[M][K] bf16, Wt[N][K] bf16. 64x64 tile, BK=64, 4 waves, 2x2 16x16 tiles/wave.
__device__ __forceinline__ void gemm_core(
    const ushort_t* __restrict__ A, const ushort_t* __restrict__ Wt,
    const float* __restrict__ bias, const float* __restrict__ R,
    float* __restrict__ Cf, ushort_t* __restrict__ Cb,
    int M, int N, int K, int act, int m0, int n0){
  __shared__ ushort_t As[64][64];
  __shared__ ushort_t Bs[64][64];
  int tid = threadIdx.x;
  int w = tid>>6, lane = tid&63;
  int wr = w>>1, wc = w&1;
  int q = lane>>4, u = lane&15;
  f32x4 acc[2][2];
  #pragma unroll
  for (int i=0;i<2;i++)
    #pragma unroll
    for (int j=0;j<2;j++)
      acc[i][j] = (f32x4){0.f,0.f,0.f,0.f};
  for (int k0 = 0; k0 < K; k0 += 64){
    #pragma unroll
    for (int i=0;i<2;i++){
      int c = tid + 256*i;
      int row = c>>3, col = (c&7)*8;
      *(uint4*)&As[row][col] = *(const uint4*)&A [(size_t)(m0+row)*K + k0 + col];
      *(uint4*)&Bs[row][col] = *(const uint4*)&Wt[(size_t)(n0+row)*K + k0 + col];
    }
    __syncthreads();
    #pragma unroll
    for (int kk=0; kk<2; kk++){
      bf16x8 af[2], bfv[2];
      #pragma unroll
      for (int i=0;i<2;i++) af[i]  = *(const bf16x8*)&As[wr*32 + i*16 + u][kk*32 + q*8];
      #pragma unroll
      for (int j=0;j<2;j++) bfv[j] = *(const bf16x8*)&Bs[wc*32 + j*16 + u][kk*32 + q*8];
      #pragma unroll
      for (int i=0;i<2;i++)
        #pragma unroll
        for (int j=0;j<2;j++)
          acc[i][j] = __builtin_amdgcn_mfma_f32_16x16x32_bf16(af[i], bfv[j], acc[i][j], 0, 0, 0);
    }
    __syncthreads();
  }
  // epilogue: C/D layout col=lane&15, row=(lane>>4)*4+reg
  #pragma unroll
  for (int i=0;i<2;i++){
    #pragma unroll
    for (int j=0;j<2;j++){
      #pragma unroll
      for (int t=0;t<4;t++){
        int m = m0 + wr*32 + i*16 + q*4 + t;
        int n = n0 + wc*32 + j*16 + u;
        float val = acc[i][j][t] + bias[n];
        if (R)   val += R[(size_t)m*N + n];
        if (act) val = gelu_f(val);
        if (Cf) Cf[(size_t)m*N + n] = val;
        if (Cb) Cb[(size_t)m*N + n] = f2b(val);
      }
    }
  }
}

__global__ __launch_bounds__(256) void gemm_kernel(
    const ushort_t* __restrict__ A, const ushort_t* __restrict__ Wt,
    const float* __restrict__ bias, const float* __restrict__ R,
    float* __restrict__ Cf, ushort_t* __restrict__ Cb,
    int M, int N, int K, int act){
  gemm_core(A, Wt, bias, R, Cf, Cb, M, N, K, act, blockIdx.y*64, blockIdx.x*64);
}

// fused QKV: grid.z picks {q,k,v}
__global__ __launch_bounds__(256) void gemm_qkv_kernel(
    const ushort_t* __restrict__ A,
    const ushort_t* __restrict__ wtq, const ushort_t* __restrict__ wtk, const ushort_t* __restrict__ wtv,
    const float* __restrict__ bq, const float* __restrict__ bk, const float* __restrict__ bv,
    float* __restrict__ qo, float* __restrict__ ko, float* __restrict__ vo){
  int z = blockIdx.z;
  const ushort_t* Wt = (z==0)?wtq:(z==1)?wtk:wtv;
  const float* bias  = (z==0)?bq :(z==1)?bk :bv;
  float* Cf          = (z==0)?qo :(z==1)?ko :vo;
  gemm_core(A, Wt, bias, nullptr, Cf, nullptr, SEQ, DIM, DIM, 0, blockIdx.y*64, blockIdx.x*64);
}

// ---------------- sliding-window attention, fp32, flash-style ---------------
// grid (SEQ/32, NH), block 256. r=tid>>3 (q-row 0..31), g=tid&7.
// scores: thread owns keys j=g*8..g*8+7 ; PV: thread owns dh slice g*4..g*4+3.
__global__ __launch_bounds__(256) void attn_kernel(const float* __restrict__ q,
    const float* __restrict__ k, const float* __restrict__ v,
    ushort_t* __restrict__ out){
  int q0 = blockIdx.x * 32;
  int h  = blockIdx.y;
  int tid = threadIdx.x;
  int r = tid >> 3, g = tid & 7;
  __shared__ float Ks[64][36];   // chunk-XOR-swizzled: orig chunk d4 at (d4^(row>>3))*4
  __shared__ float Vs[64][36];
  __shared__ float Ss[32][33];

  float qreg[32];
  {
    const float* qp = q + (size_t)(q0 + r)*DIM + h*DHD;
    #pragma unroll
    for(int d=0; d<32; d+=4){
      float4 t = *(const float4*)(qp + d);
      qreg[d]=t.x; qreg[d+1]=t.y; qreg[d+2]=t.z; qreg[d+3]=t.w;
    }
  }
  const float scale = 0.17677669529663687f; // 1/sqrt(32)
  float m = -INFINITY, l = 0.f;
  float o[4] = {0.f,0.f,0.f,0.f};

  int lo = q0 - 256; if (lo < 0) lo = 0;
  int hi = q0 + 31 + 256; if (hi > SEQ-1) hi = SEQ-1;
  int kt0 = (lo >> 6) << 6;
  int kt1 = (hi >> 6) << 6;

  for (int kt = kt0; kt <= kt1; kt += 64){
    __syncthreads();
    #pragma unroll
    for (int i=0;i<2;i++){
      int c = tid + 256*i;
      int rr = c>>3, d4 = c&7;
      const float* kp = k + (size_t)(kt+rr)*DIM + h*DHD + d4*4;
      const float* vp = v + (size_t)(kt+rr)*DIM + h*DHD + d4*4;
      float4 kv = *(const float4*)kp;
      float4 vv = *(const float4*)vp;
      *(float4*)&Ks[rr][((d4 ^ (rr>>3)) & 7)*4] = kv;
      *(float4*)&Vs[rr][d4*4] = vv;
    }
    __syncthreads();

    float sc[8];
    float smax = -INFINITY;
    #pragma unroll
    for (int jj=0; jj<8; jj++){
      int j = g*8 + jj;
      int sw = j>>3;    // == g
      float s = 0.f;
      #pragma unroll
      for (int d4=0; d4<8; d4++){
        float4 kk4 = *(const float4*)&Ks[j][((d4 ^ sw) & 7)*4];
        s = fmaf(qreg[d4*4+0], kk4.x, s);
        s = fmaf(qreg[d4*4+1], kk4.y, s);
        s = fmaf(qreg[d4*4+2], kk4.z, s);
        s = fmaf(qreg[d4*4+3], kk4.w, s);
      }
      s *= scale;
      int diff = (q0 + r) - (kt + j); if (diff < 0) diff = -diff;
      if (diff > 256) s = -INFINITY;
      sc[jj] = s;
      smax = fmaxf(smax, s);
    }
    smax = fmaxf(smax, __shfl_xor(smax, 1));
    smax = fmaxf(smax, __shfl_xor(smax, 2));
    smax = fmaxf(smax, __shfl_xor(smax, 4));
    float new_m = fmaxf(m, smax);
    float alpha = expf(m - new_m);
    float rowsum = 0.f;
    #pragma unroll
    for (int jj=0; jj<8; jj++){
      float p = expf(sc[jj] - new_m);
      Ss[r][g*8+jj] = p;
      rowsum += p;
    }
    rowsum += __shfl_xor(rowsum,1);
    rowsum += __shfl_xor(rowsum,2);
    rowsum += __shfl_xor(rowsum,4);
    l = l*alpha + rowsum;
    m = new_m;
    #pragma unroll
    for (int i=0;i<4;i++) o[i]*=alpha;
    __syncthreads();

    int c0 = g*4;
    for (int j=0;j<64;j++){
      float pj = Ss[r][j];
      float4 v4 = *(const float4*)&Vs[j][c0];
      o[0] = fmaf(pj, v4.x, o[0]);
      o[1] = fmaf(pj, v4.y, o[1]);
      o[2] = fmaf(pj, v4.z, o[2]);
      o[3] = fmaf(pj, v4.w, o[3]);
    }
  }
  float rl = 1.0f / l;
  ushort_t* op = out + (size_t)(q0+r)*DIM + h*DHD + g*4;
  #pragma unroll
  for (int i=0;i<4;i++) op[i] = f2b(o[i]*rl);
}

extern "C" void kernel_launch(void* const* d_in, const int* in_sizes, int n_in,
                              void* d_out, int out_size, void* d_ws, size_t ws_size,
                              hipStream_t stream) {
  const float* x  = (const float*)d_in[0];
  const float* wq = (const float*)d_in[1];
  const float* bq = (const float*)d_in[2];
  const float* wk = (const float*)d_in[3];
  const float* bk = (const float*)d_in[4];
  const float* wv = (const float*)d_in[5];
  const float* bv = (const float*)d_in[6];
  const float* wo = (const float*)d_in[7];
  const float* bo = (const float*)d_in[8];
  const float* w1 = (const float*)d_in[9];
  const float* b1 = (const float*)d_in[10];
  const float* w2 = (const float*)d_in[11];
  const float* b2 = (const float*)d_in[12];
  float* out = (float*)d_out;
  float* ws  = (float*)d_ws;

  // workspace layout (float offsets)
  ushort_t* wt    = (ushort_t*)ws;                    // 3,145,728 ushorts (1.57M floats)
  ushort_t* abuf  = (ushort_t*)(ws + 1572864);        // 1M ushorts  (LN1/attn/LN2 bf16)
  ushort_t* ffbf  = (ushort_t*)(ws + 2097152);        // 4M ushorts  (FFN1 out bf16)
  float* qb = ws + 4194304;                           // q  -> later h1
  float* kb = ws + 5242880;                           // k  -> later h2
  float* vb = ws + 6291456;                           // v
  float* hb = ws + 7340032;                           // layer carry

  const ushort_t* w1t_base = wt + 1048576;
  const ushort_t* w2t_base = wt + 2097152;

  const dim3 blk(256);
  wconv_kernel<<<768, blk, 0, stream>>>(wq, wk, wv, wo, w1, w2, wt);

  for (int l = 0; l < NLAYER; l++){
    const float* hin = (l == 0) ? x : hb;
    const ushort_t* lwq = wt + (size_t)(0*NLAYER + l)*65536;
    const ushort_t* lwk = wt + (size_t)(1*NLAYER + l)*65536;
    const ushort_t* lwv = wt + (size_t)(2*NLAYER + l)*65536;
    const ushort_t* lwo = wt + (size_t)(3*NLAYER + l)*65536;
    const ushort_t* lw1 = w1t_base + (size_t)l*262144;
    const ushort_t* lw2 = w2t_base + (size_t)l*262144;

    // n = LN(h) -> bf16
    ln_kernel<<<SEQ/4, blk, 0, stream>>>(hin, nullptr, abuf);
    // q,k,v = n@W + b  (fp32 out)
    gemm_qkv_kernel<<<dim3(4,64,3), blk, 0, stream>>>(abuf, lwq, lwk, lwv,
        bq + (size_t)l*DIM, bk + (size_t)l*DIM, bv + (size_t)l*DIM, qb, kb, vb);
    // attention -> bf16 abuf
    attn_kernel<<<dim3(SEQ/32, NH), blk, 0, stream>>>(qb, kb, vb, abuf);
    // h1 = h + attn@wo + bo  -> qb (fp32)
    gemm_kernel<<<dim3(4,64), blk, 0, stream>>>(abuf, lwo, bo + (size_t)l*DIM,
        hin, qb, nullptr, SEQ, DIM, DIM, 0);
    // h2 = LN(h1) -> kb (fp32) + abuf (bf16)
    ln_kernel<<<SEQ/4, blk, 0, stream>>>(qb, kb, abuf);
    // ff = gelu(h2@w1 + b1) -> bf16
    gemm_kernel<<<dim3(16,64), blk, 0, stream>>>(abuf, lw1, b1 + (size_t)l*FFD,
        nullptr, nullptr, ffbf, SEQ, FFD, DIM, 1);
    // h_out = h2 + ff@w2 + b2
    float* hout = (l == NLAYER-1) ? out : hb;
    gemm_kernel<<<dim3(4,64), blk, 0, stream>>>(ffbf, lw2, b2 + (size_t)l*DIM,
        kb, hout, nullptr, SEQ, DIM, FFD, 0);
  }
}